// Round 1
// baseline (12.696 us; speedup 1.0000x reference)
//
#include <hip/hip_runtime.h>

// Net_26774826123689: the reference ends with log_softmax over axis=1 of an
// (8,1) tensor. A softmax over a single-class axis is identically zero
// (x - logsumexp(x) == 0 exactly), so the reference output is the constant
// zero vector of length out_size (=8) regardless of inputs. All upstream
// compute (spline conv x2, pooling, MLP) is dead code. The optimal kernel
// writes zeros to d_out each call (d_out is poisoned to 0xAA before timing,
// so the write must happen on every replay).

__global__ void net_write_zeros(float* __restrict__ out, int n) {
    int i = blockIdx.x * blockDim.x + threadIdx.x;
    if (i < n) out[i] = 0.0f;
}

extern "C" void kernel_launch(void* const* d_in, const int* in_sizes, int n_in,
                              void* d_out, int out_size, void* d_ws, size_t ws_size,
                              hipStream_t stream) {
    (void)d_in; (void)in_sizes; (void)n_in; (void)d_ws; (void)ws_size;
    float* out = (float*)d_out;
    // out_size == 8; one 64-wide wave (block = wave multiple per G11).
    net_write_zeros<<<dim3(1), dim3(64), 0, stream>>>(out, out_size);
}